// Round 8
// baseline (116.377 us; speedup 1.0000x reference)
//
#include <hip/hip_runtime.h>
#include <hip/hip_bf16.h>

#define BATCH 8
#define CH    256
#define NN    1024
#define DD    32

// ws layout (bf16 shorts):
//   qT [b][i][d]   (scale*log2e folded)      512 KB
//   kT [b][j][d]   (rp + bias folded)        512 KB
//   v2 [b][jt=32][ct=16][lane=64][jj=8]      4 MB   (MFMA A-frag-ready)
//   wf [mf=20][kc=8][lane=64][jj=8]          160 KB (W in A-frag-ready bf16)
#define QT_OFF 0
#define KT_OFF (BATCH * NN * DD)
#define V_OFF  (2 * BATCH * NN * DD)
#define V2_B   (NN * CH)                       // shorts per batch in v2
#define WF_OFF (V_OFF + BATCH * V2_B)          // 2621440

// 1/sqrt(32) * log2(e): softmax via exp2 (v_exp_f32 is native 2^x)
#define SCALE_Q (0.17677669529663687f * 1.4426950408889634f)
#define INV31 (1.0f / 31.0f)

typedef __attribute__((ext_vector_type(4))) float f32x4;
typedef __attribute__((ext_vector_type(8))) short bf16x8;

__device__ __forceinline__ unsigned int packbf2(float lo, float hi) {
    __hip_bfloat162 h = __float22bfloat162_rn(make_float2(lo, hi));
    union { __hip_bfloat162 h; unsigned int u; } cv; cv.h = h;
    return cv.u;
}
__device__ __forceinline__ unsigned short f2bf(float x) {
    union { float f; unsigned int u; } v; v.f = x;
    return (unsigned short)((v.u + 0x7FFFu + ((v.u >> 16) & 1u)) >> 16);
}

// ---------------------------------------------------------------------------
// Kernel W: repack W_all (320x256 fp32) into MFMA-A-fragment-ready bf16.
// ---------------------------------------------------------------------------
__global__ __launch_bounds__(256) void wrepack_kernel(
    const float* __restrict__ Wq, const float* __restrict__ Wk,
    const float* __restrict__ Wv, unsigned short* __restrict__ ws)
{
    const int gid = blockIdx.x * 256 + threadIdx.x;   // 0..20479
    const int e = gid * 4;
    const int m = e >> 8;
    const int k = e & 255;
    const float* src = (m < 32) ? (Wq + m * CH + k)
                     : (m < 64) ? (Wk + (m - 32) * CH + k)
                                : (Wv + (m - 64) * CH + k);
    const float4 w = *(const float4*)src;
    const int mf = m >> 4, kc = k >> 5;
    const int lf = ((k >> 3) & 3) * 16 + (m & 15);
    const int jj = k & 7;                              // 0 or 4
    uint2 st = { packbf2(w.x, w.y), packbf2(w.z, w.w) };
    *(uint2*)(ws + WF_OFF + ((size_t)(mf * 8 + kc) * 64 + lf) * 8 + jj) = st;
}

// ---------------------------------------------------------------------------
// Kernel P: MFMA projection, double-buffered across kc.
// ---------------------------------------------------------------------------
__global__ __launch_bounds__(256, 2) void proj_kernel(
    const float* __restrict__ x,
    const float* __restrict__ bq, const float* __restrict__ bk,
    const float* __restrict__ bv, const float* __restrict__ Wr,
    unsigned short* __restrict__ ws)
{
    const int nt   = blockIdx.x;   // 0..63
    const int b    = blockIdx.y;   // 0..7
    const int tid  = threadIdx.x;
    const int wv   = tid >> 6;     // 0..3 (m-group)
    const int lane = tid & 63;
    const int n16  = lane & 15;
    const int q4   = lane >> 4;
    const int n    = nt * 16 + n16;

    f32x4 acc[5];
#pragma unroll
    for (int t = 0; t < 5; t++) acc[t] = (f32x4){0.f, 0.f, 0.f, 0.f};

    const unsigned short* wfl = ws + WF_OFF + (size_t)lane * 8;
    const float* xb = x + (size_t)b * CH * NN + n;

    float  bx[2][8];
    bf16x8 af[2][5];
#pragma unroll
    for (int jj = 0; jj < 8; jj++)
        bx[0][jj] = xb[(size_t)(q4 * 8 + jj) * NN];
#pragma unroll
    for (int t = 0; t < 5; t++)
        af[0][t] = *(const bf16x8*)(wfl + (size_t)((wv * 5 + t) * 8) * 512);

#pragma unroll
    for (int kc = 0; kc < 8; kc++) {
        const int s = kc & 1;
        if (kc < 7) {
            const int kofs = (kc + 1) * 32 + q4 * 8;
#pragma unroll
            for (int jj = 0; jj < 8; jj++)
                bx[s ^ 1][jj] = xb[(size_t)(kofs + jj) * NN];
#pragma unroll
            for (int t = 0; t < 5; t++)
                af[s ^ 1][t] = *(const bf16x8*)(wfl + (size_t)((wv * 5 + t) * 8 + kc + 1) * 512);
        }
        union { unsigned int u[4]; bf16x8 v; } bf;
#pragma unroll
        for (int p = 0; p < 4; p++) bf.u[p] = packbf2(bx[s][2 * p], bx[s][2 * p + 1]);
#pragma unroll
        for (int t = 0; t < 5; t++)
            acc[t] = __builtin_amdgcn_mfma_f32_16x16x32_bf16(af[s][t], bf.v, acc[t], 0, 0, 0);
    }

    const int jt  = n >> 5;
    const int q4p = (n >> 3) & 3;
    const int jj  = n & 7;
#pragma unroll
    for (int t = 0; t < 5; t++) {
        const int mf = wv * 5 + t;
        const int mb = mf * 16 + q4 * 4;
        if (mb < 32) {
            const float r0 = (acc[t][0] + bq[mb + 0]) * SCALE_Q;
            const float r1 = (acc[t][1] + bq[mb + 1]) * SCALE_Q;
            const float r2 = (acc[t][2] + bq[mb + 2]) * SCALE_Q;
            const float r3 = (acc[t][3] + bq[mb + 3]) * SCALE_Q;
            uint2 st = { packbf2(r0, r1), packbf2(r2, r3) };
            *(uint2*)(ws + QT_OFF + (size_t)(b * NN + n) * DD + mb) = st;
        } else if (mb < 64) {
            const int d = mb - 32;
            const float An = (float)(n >> 5) * INV31;
            const float Bn = (float)(n & 31) * INV31;
            float r[4];
#pragma unroll
            for (int rr = 0; rr < 4; rr++)
                r[rr] = acc[t][rr] + bk[d + rr] - An * Wr[2 * (d + rr)] - Bn * Wr[2 * (d + rr) + 1];
            uint2 st = { packbf2(r[0], r[1]), packbf2(r[2], r[3]) };
            *(uint2*)(ws + KT_OFF + (size_t)(b * NN + n) * DD + d) = st;
        } else {
            const int c = mb - 64;
#pragma unroll
            for (int rr = 0; rr < 4; rr++) {
                const int cc = c + rr;
                const size_t off = V_OFF + (size_t)b * V2_B
                                 + (size_t)jt * 8192 + (size_t)(cc >> 4) * 512
                                 + (size_t)(q4p * 16 + (cc & 15)) * 8 + jj;
                ws[off] = f2bf(acc[t][rr] + bv[cc]);
            }
        }
    }
}

// ---------------------------------------------------------------------------
// Kernel B: MFMA flash attention. Block = (b, i-group of 32, c-quarter):
// grid (8,128) -> 1024 blocks, 4/CU, 16 waves/CU. 4 waves = (j-half)x(c-32).
// Each wave: 2 i-tiles x 32 c x 512 j — ka/va fragments reused across both
// i-tiles (halves V L2 traffic vs 16-i blocks; 8 MFMA : 4 KB loads/chunk).
// XCD affinity: linear block id === b (mod 8) keeps batch K/V L2-resident.
// No-max softmax via exp2 (logits bounded ~|6|), 1-deep prefetch, 1 barrier.
// ---------------------------------------------------------------------------
__global__ __launch_bounds__(256, 4) void attn_kernel(
    const float* __restrict__ x,
    const float* __restrict__ gamma,
    const unsigned short* __restrict__ ws,
    float* __restrict__ out)
{
    const int b    = blockIdx.x;        // 0..7  (XCD affinity)
    const int by   = blockIdx.y;        // 0..127
    const int ig   = by >> 2;           // i-group 0..31 (32 queries)
    const int cq   = by & 3;            // c-quarter
    const int tid  = threadIdx.x;
    const int jh   = tid >> 7;          // j-half (waves 0,1 vs 2,3)
    const int cw   = (tid >> 6) & 1;    // c-32 within quarter
    const int lane = tid & 63;
    const int n    = lane & 15;         // col index: i (within tile)
    const int q4   = lane >> 4;
    const int i0   = ig * 32;
    const int cb   = cq * 64 + cw * 32;

    __shared__ float accL[2 * 16 * 64];  // 8 KB: [cw][it*8 + t*4 + r][lane]
    __shared__ float lL[32];

    const unsigned short* qT = ws + QT_OFF + (size_t)b * NN * DD;
    const unsigned short* kT = ws + KT_OFF + (size_t)b * NN * DD + (size_t)jh * 512 * DD;
    const unsigned short* vb = ws + V_OFF + (size_t)b * V2_B
                             + (size_t)jh * 16 * 8192 + (size_t)(cb >> 4) * 512
                             + (size_t)lane * 8;

    const bf16x8 qf0 = *(const bf16x8*)(qT + (size_t)(i0 + n) * DD + q4 * 8);
    const bf16x8 qf1 = *(const bf16x8*)(qT + (size_t)(i0 + 16 + n) * DD + q4 * 8);

    f32x4 acc0[2], acc1[2];
#pragma unroll
    for (int t = 0; t < 2; t++) {
        acc0[t] = (f32x4){0.f, 0.f, 0.f, 0.f};
        acc1[t] = (f32x4){0.f, 0.f, 0.f, 0.f};
    }
    float lsum0 = 0.f, lsum1 = 0.f;

    // 1-deep prefetch (last-iter over-reads land inside ws — harmless)
    bf16x8 ka0 = *(const bf16x8*)(kT + (size_t)(n) * DD + q4 * 8);
    bf16x8 ka1 = *(const bf16x8*)(kT + (size_t)(16 + n) * DD + q4 * 8);
    bf16x8 va[2];
#pragma unroll
    for (int t = 0; t < 2; t++)
        va[t] = *(const bf16x8*)(vb + t * 512);

    const int qh2 = (q4 & 1) * 2;
    int src[4];
#pragma unroll
    for (int t = 0; t < 4; t++) src[t] = (qh2 + (t >> 1)) * 16 + n;

#pragma unroll 4
    for (int ch = 0; ch < 16; ch++) {
        const bf16x8 ka0c = ka0, ka1c = ka1;
        bf16x8 vac[2];
#pragma unroll
        for (int t = 0; t < 2; t++) vac[t] = va[t];

        {   // prefetch next chunk
            const int j0 = (ch + 1) * 32;
            ka0 = *(const bf16x8*)(kT + (size_t)(j0 + n) * DD + q4 * 8);
            ka1 = *(const bf16x8*)(kT + (size_t)(j0 + 16 + n) * DD + q4 * 8);
#pragma unroll
            for (int t = 0; t < 2; t++)
                va[t] = *(const bf16x8*)(vb + (ch + 1) * 8192 + t * 512);
        }

        const f32x4 z = {0.f, 0.f, 0.f, 0.f};
        f32x4 s0a = __builtin_amdgcn_mfma_f32_16x16x32_bf16(ka0c, qf0, z, 0, 0, 0);
        f32x4 s1a = __builtin_amdgcn_mfma_f32_16x16x32_bf16(ka1c, qf0, z, 0, 0, 0);
        f32x4 s0b = __builtin_amdgcn_mfma_f32_16x16x32_bf16(ka0c, qf1, z, 0, 0, 0);
        f32x4 s1b = __builtin_amdgcn_mfma_f32_16x16x32_bf16(ka1c, qf1, z, 0, 0, 0);

        float p0a[4], p1a[4], p0b[4], p1b[4];
#pragma unroll
        for (int r = 0; r < 4; r++) {
            p0a[r] = exp2f(s0a[r]);
            p1a[r] = exp2f(s1a[r]);
            p0b[r] = exp2f(s0b[r]);
            p1b[r] = exp2f(s1b[r]);
            lsum0 += p0a[r] + p1a[r];
            lsum1 += p0b[r] + p1b[r];
        }

        unsigned int pk0a[2] = { packbf2(p0a[0], p0a[1]), packbf2(p0a[2], p0a[3]) };
        unsigned int pk1a[2] = { packbf2(p1a[0], p1a[1]), packbf2(p1a[2], p1a[3]) };
        unsigned int pk0b[2] = { packbf2(p0b[0], p0b[1]), packbf2(p0b[2], p0b[3]) };
        unsigned int pk1b[2] = { packbf2(p1b[0], p1b[1]), packbf2(p1b[2], p1b[3]) };
        union { unsigned int u[4]; bf16x8 v; } pfa, pfb;
#pragma unroll
        for (int t = 0; t < 4; t++) {
            const unsigned int loa = (unsigned int)__shfl((int)pk0a[t & 1], src[t], 64);
            const unsigned int hia = (unsigned int)__shfl((int)pk1a[t & 1], src[t], 64);
            const unsigned int lob = (unsigned int)__shfl((int)pk0b[t & 1], src[t], 64);
            const unsigned int hib = (unsigned int)__shfl((int)pk1b[t & 1], src[t], 64);
            pfa.u[t] = (q4 >= 2) ? hia : loa;
            pfb.u[t] = (q4 >= 2) ? hib : lob;
        }

#pragma unroll
        for (int t = 0; t < 2; t++) {
            acc0[t] = __builtin_amdgcn_mfma_f32_16x16x32_bf16(vac[t], pfa.v, acc0[t], 0, 0, 0);
            acc1[t] = __builtin_amdgcn_mfma_f32_16x16x32_bf16(vac[t], pfb.v, acc1[t], 0, 0, 0);
        }
    }

    lsum0 += __shfl_xor(lsum0, 16, 64);
    lsum0 += __shfl_xor(lsum0, 32, 64);
    lsum1 += __shfl_xor(lsum1, 16, 64);
    lsum1 += __shfl_xor(lsum1, 32, 64);

    if (jh == 1) {
#pragma unroll
        for (int t = 0; t < 2; t++)
#pragma unroll
            for (int r = 0; r < 4; r++) {
                accL[(cw * 16 + t * 4 + r) * 64 + lane]     = acc0[t][r];
                accL[(cw * 16 + 8 + t * 4 + r) * 64 + lane] = acc1[t][r];
            }
        if (cw == 0 && lane < 16) lL[lane] = lsum0;
        if (cw == 1 && lane < 16) lL[16 + lane] = lsum1;
    }
    __syncthreads();

    if (jh == 0) {
        const float g = gamma[0];
        const float rl0 = g / (lsum0 + lL[n]);
        const float rl1 = g / (lsum1 + lL[16 + n]);
#pragma unroll
        for (int t = 0; t < 2; t++) {
#pragma unroll
            for (int r = 0; r < 4; r++) {
                const int c = cb + t * 16 + q4 * 4 + r;
                const size_t base = (size_t)(b * CH + c) * NN + i0 + n;
                const float a0 = acc0[t][r] + accL[(cw * 16 + t * 4 + r) * 64 + lane];
                const float a1 = acc1[t][r] + accL[(cw * 16 + 8 + t * 4 + r) * 64 + lane];
                out[base]      = a0 * rl0 + x[base];
                out[base + 16] = a1 * rl1 + x[base + 16];
            }
        }
    }
}

extern "C" void kernel_launch(void* const* d_in, const int* in_sizes, int n_in,
                              void* d_out, int out_size, void* d_ws, size_t ws_size,
                              hipStream_t stream) {
    (void)in_sizes; (void)n_in; (void)out_size; (void)ws_size;
    const float* x     = (const float*)d_in[0];
    const float* Wq    = (const float*)d_in[1];
    const float* bq    = (const float*)d_in[2];
    const float* Wk    = (const float*)d_in[3];
    const float* bk    = (const float*)d_in[4];
    const float* Wv    = (const float*)d_in[5];
    const float* bv    = (const float*)d_in[6];
    const float* Wr    = (const float*)d_in[7];
    // d_in[8] = br: j-constant logit shift -> softmax-invariant, dropped.
    const float* gamma = (const float*)d_in[9];
    float* out = (float*)d_out;
    unsigned short* ws = (unsigned short*)d_ws;

    wrepack_kernel<<<80, 256, 0, stream>>>(Wq, Wk, Wv, ws);
    proj_kernel<<<dim3(64, 8), 256, 0, stream>>>(x, bq, bk, bv, Wr, ws);
    attn_kernel<<<dim3(8, 128), 256, 0, stream>>>(x, gamma, ws, out);
}

// Round 9
// 109.572 us; speedup vs baseline: 1.0621x; 1.0621x over previous
//
#include <hip/hip_runtime.h>
#include <hip/hip_bf16.h>

#define BATCH 8
#define CH    256
#define NN    1024
#define DD    32

// ws layout (bf16 shorts):
//   qT [b][i][d]   (scale*log2e folded)      512 KB
//   kT [b][j][d]   (rp + bias folded)        512 KB
//   v2 [b][jt32=32][ct=16][lane=64][sub=2][jj=4]  4 MB
//        element (c,j): jt=j>>5, ct=c>>4, lane=((j>>2)&3)*16+(c&15),
//                       sub=(j>>4)&1, jj=j&3
//        (16x16x16 A-frag-ready: lane&15 = c, lane>>4 = j-quad, 4 j each;
//         sub picks the 16-j half of a 32-j chunk; b128 load grabs both)
//   wf [mf=20][kc=8][lane=64][jj=8]          160 KB (W in x32 A-frag bf16)
#define QT_OFF 0
#define KT_OFF (BATCH * NN * DD)
#define V_OFF  (2 * BATCH * NN * DD)
#define V2_B   (NN * CH)                       // shorts per batch in v2
#define WF_OFF (V_OFF + BATCH * V2_B)          // 2621440

// 1/sqrt(32) * log2(e): softmax via exp2 (v_exp_f32 is native 2^x)
#define SCALE_Q (0.17677669529663687f * 1.4426950408889634f)
#define INV31 (1.0f / 31.0f)

typedef __attribute__((ext_vector_type(4))) float f32x4;
typedef __attribute__((ext_vector_type(8))) short bf16x8;
typedef __attribute__((ext_vector_type(4))) short bf16x4;

__device__ __forceinline__ unsigned int packbf2(float lo, float hi) {
    __hip_bfloat162 h = __float22bfloat162_rn(make_float2(lo, hi));
    union { __hip_bfloat162 h; unsigned int u; } cv; cv.h = h;
    return cv.u;
}
__device__ __forceinline__ unsigned short f2bf(float x) {
    union { float f; unsigned int u; } v; v.f = x;
    return (unsigned short)((v.u + 0x7FFFu + ((v.u >> 16) & 1u)) >> 16);
}

// ---------------------------------------------------------------------------
// Kernel W: repack W_all (320x256 fp32) into MFMA-A-fragment-ready bf16.
// ---------------------------------------------------------------------------
__global__ __launch_bounds__(256) void wrepack_kernel(
    const float* __restrict__ Wq, const float* __restrict__ Wk,
    const float* __restrict__ Wv, unsigned short* __restrict__ ws)
{
    const int gid = blockIdx.x * 256 + threadIdx.x;   // 0..20479
    const int e = gid * 4;
    const int m = e >> 8;
    const int k = e & 255;
    const float* src = (m < 32) ? (Wq + m * CH + k)
                     : (m < 64) ? (Wk + (m - 32) * CH + k)
                                : (Wv + (m - 64) * CH + k);
    const float4 w = *(const float4*)src;
    const int mf = m >> 4, kc = k >> 5;
    const int lf = ((k >> 3) & 3) * 16 + (m & 15);
    const int jj = k & 7;                              // 0 or 4
    uint2 st = { packbf2(w.x, w.y), packbf2(w.z, w.w) };
    *(uint2*)(ws + WF_OFF + ((size_t)(mf * 8 + kc) * 64 + lf) * 8 + jj) = st;
}

// ---------------------------------------------------------------------------
// Kernel P: MFMA projection, double-buffered across kc.
// ---------------------------------------------------------------------------
__global__ __launch_bounds__(256, 2) void proj_kernel(
    const float* __restrict__ x,
    const float* __restrict__ bq, const float* __restrict__ bk,
    const float* __restrict__ bv, const float* __restrict__ Wr,
    unsigned short* __restrict__ ws)
{
    const int nt   = blockIdx.x;   // 0..63
    const int b    = blockIdx.y;   // 0..7
    const int tid  = threadIdx.x;
    const int wv   = tid >> 6;     // 0..3 (m-group)
    const int lane = tid & 63;
    const int n16  = lane & 15;
    const int q4   = lane >> 4;
    const int n    = nt * 16 + n16;

    f32x4 acc[5];
#pragma unroll
    for (int t = 0; t < 5; t++) acc[t] = (f32x4){0.f, 0.f, 0.f, 0.f};

    const unsigned short* wfl = ws + WF_OFF + (size_t)lane * 8;
    const float* xb = x + (size_t)b * CH * NN + n;

    float  bx[2][8];
    bf16x8 af[2][5];
#pragma unroll
    for (int jj = 0; jj < 8; jj++)
        bx[0][jj] = xb[(size_t)(q4 * 8 + jj) * NN];
#pragma unroll
    for (int t = 0; t < 5; t++)
        af[0][t] = *(const bf16x8*)(wfl + (size_t)((wv * 5 + t) * 8) * 512);

#pragma unroll
    for (int kc = 0; kc < 8; kc++) {
        const int s = kc & 1;
        if (kc < 7) {
            const int kofs = (kc + 1) * 32 + q4 * 8;
#pragma unroll
            for (int jj = 0; jj < 8; jj++)
                bx[s ^ 1][jj] = xb[(size_t)(kofs + jj) * NN];
#pragma unroll
            for (int t = 0; t < 5; t++)
                af[s ^ 1][t] = *(const bf16x8*)(wfl + (size_t)((wv * 5 + t) * 8 + kc + 1) * 512);
        }
        union { unsigned int u[4]; bf16x8 v; } bf;
#pragma unroll
        for (int p = 0; p < 4; p++) bf.u[p] = packbf2(bx[s][2 * p], bx[s][2 * p + 1]);
#pragma unroll
        for (int t = 0; t < 5; t++)
            acc[t] = __builtin_amdgcn_mfma_f32_16x16x32_bf16(af[s][t], bf.v, acc[t], 0, 0, 0);
    }

    const int jj4 = n & 3;          // v2 sub-indices for this thread's j (= n)
    const int sub = (n >> 4) & 1;
    const int lq  = (n >> 2) & 3;
    const int jt  = n >> 5;
#pragma unroll
    for (int t = 0; t < 5; t++) {
        const int mf = wv * 5 + t;
        const int mb = mf * 16 + q4 * 4;
        if (mb < 32) {
            const float r0 = (acc[t][0] + bq[mb + 0]) * SCALE_Q;
            const float r1 = (acc[t][1] + bq[mb + 1]) * SCALE_Q;
            const float r2 = (acc[t][2] + bq[mb + 2]) * SCALE_Q;
            const float r3 = (acc[t][3] + bq[mb + 3]) * SCALE_Q;
            uint2 st = { packbf2(r0, r1), packbf2(r2, r3) };
            *(uint2*)(ws + QT_OFF + (size_t)(b * NN + n) * DD + mb) = st;
        } else if (mb < 64) {
            const int d = mb - 32;
            const float An = (float)(n >> 5) * INV31;
            const float Bn = (float)(n & 31) * INV31;
            float r[4];
#pragma unroll
            for (int rr = 0; rr < 4; rr++)
                r[rr] = acc[t][rr] + bk[d + rr] - An * Wr[2 * (d + rr)] - Bn * Wr[2 * (d + rr) + 1];
            uint2 st = { packbf2(r[0], r[1]), packbf2(r[2], r[3]) };
            *(uint2*)(ws + KT_OFF + (size_t)(b * NN + n) * DD + d) = st;
        } else {
            const int c = mb - 64;
#pragma unroll
            for (int rr = 0; rr < 4; rr++) {
                const int cc = c + rr;
                const size_t off = V_OFF + (size_t)b * V2_B
                                 + (size_t)jt * 8192 + (size_t)(cc >> 4) * 512
                                 + (size_t)(lq * 16 + (cc & 15)) * 8 + sub * 4 + jj4;
                ws[off] = f2bf(acc[t][rr] + bv[cc]);
            }
        }
    }
}

// ---------------------------------------------------------------------------
// Kernel B: MFMA flash attention (R7 shape). Block = (b, i-group 16, c-half),
// grid (8,128) -> 1024 blocks, 4/CU. 4 waves = (j-half) x (c-64).
// PV uses v_mfma_f32_16x16x16_bf16: the S^T C-layout (4 j-rows/lane at
// quad*4) IS the K=16 B-operand layout, so exp(S) feeds PV with ZERO
// cross-lane shuffles — the packed bf16 pairs are the fragment.
// XCD affinity: linear block id === b (mod 8). No-max softmax via exp2.
// ---------------------------------------------------------------------------
__global__ __launch_bounds__(256, 4) void attn_kernel(
    const float* __restrict__ x,
    const float* __restrict__ gamma,
    const unsigned short* __restrict__ ws,
    float* __restrict__ out)
{
    const int b    = blockIdx.x;        // 0..7  (XCD affinity)
    const int by   = blockIdx.y;        // 0..127
    const int ig   = by >> 1;           // i-group 0..63
    const int cs   = by & 1;            // c-half
    const int tid  = threadIdx.x;
    const int jh   = tid >> 7;          // j-half (waves 0,1 vs 2,3)
    const int cw   = (tid >> 6) & 1;    // c-64 within half
    const int lane = tid & 63;
    const int n    = lane & 15;         // col index: i (within tile)
    const int q4   = lane >> 4;
    const int i0   = ig * 16;
    const int cb   = cs * 128 + cw * 64;

    __shared__ float accL[2 * 16 * 64];  // 8 KB: [cw][reg][lane]
    __shared__ float lL[16];

    const unsigned short* qT = ws + QT_OFF + (size_t)b * NN * DD;
    const unsigned short* kT = ws + KT_OFF + (size_t)b * NN * DD + (size_t)jh * 512 * DD;
    const unsigned short* vb = ws + V_OFF + (size_t)b * V2_B
                             + (size_t)jh * 16 * 8192 + (size_t)(cb >> 4) * 512
                             + (size_t)lane * 8;

    const bf16x8 qf = *(const bf16x8*)(qT + (size_t)(i0 + n) * DD + q4 * 8);

    f32x4 acc[4];
#pragma unroll
    for (int t = 0; t < 4; t++) acc[t] = (f32x4){0.f, 0.f, 0.f, 0.f};
    float lsum = 0.f;

    // 1-deep prefetch (last-iter over-reads land inside ws — harmless)
    bf16x8 ka0 = *(const bf16x8*)(kT + (size_t)(n) * DD + q4 * 8);
    bf16x8 ka1 = *(const bf16x8*)(kT + (size_t)(16 + n) * DD + q4 * 8);
    bf16x8 va[4];
#pragma unroll
    for (int t = 0; t < 4; t++)
        va[t] = *(const bf16x8*)(vb + t * 512);

#pragma unroll 4
    for (int ch = 0; ch < 16; ch++) {
        const bf16x8 ka0c = ka0, ka1c = ka1;
        bf16x8 vac[4];
#pragma unroll
        for (int t = 0; t < 4; t++) vac[t] = va[t];

        {   // prefetch next chunk
            const int j0 = (ch + 1) * 32;
            ka0 = *(const bf16x8*)(kT + (size_t)(j0 + n) * DD + q4 * 8);
            ka1 = *(const bf16x8*)(kT + (size_t)(j0 + 16 + n) * DD + q4 * 8);
#pragma unroll
            for (int t = 0; t < 4; t++)
                va[t] = *(const bf16x8*)(vb + (ch + 1) * 8192 + t * 512);
        }

        const f32x4 z = {0.f, 0.f, 0.f, 0.f};
        f32x4 s0 = __builtin_amdgcn_mfma_f32_16x16x32_bf16(ka0c, qf, z, 0, 0, 0);
        f32x4 s1 = __builtin_amdgcn_mfma_f32_16x16x32_bf16(ka1c, qf, z, 0, 0, 0);

        float p0[4], p1[4];
#pragma unroll
        for (int r = 0; r < 4; r++) {
            p0[r] = exp2f(s0[r]);
            p1[r] = exp2f(s1[r]);
            lsum += p0[r] + p1[r];
        }

        // P C-layout == K=16 B-operand layout: pack and go, no shuffles.
        union { unsigned int u[2]; bf16x4 v; } pk0, pk1;
        pk0.u[0] = packbf2(p0[0], p0[1]); pk0.u[1] = packbf2(p0[2], p0[3]);
        pk1.u[0] = packbf2(p1[0], p1[1]); pk1.u[1] = packbf2(p1[2], p1[3]);

#pragma unroll
        for (int t = 0; t < 4; t++) {
            union { bf16x8 w; bf16x4 h[2]; } vs; vs.w = vac[t];
            acc[t] = __builtin_amdgcn_mfma_f32_16x16x16bf16_1k(vs.h[0], pk0.v, acc[t], 0, 0, 0);
            acc[t] = __builtin_amdgcn_mfma_f32_16x16x16bf16_1k(vs.h[1], pk1.v, acc[t], 0, 0, 0);
        }
    }

    lsum += __shfl_xor(lsum, 16, 64);
    lsum += __shfl_xor(lsum, 32, 64);

    if (jh == 1) {
#pragma unroll
        for (int t = 0; t < 4; t++)
#pragma unroll
            for (int r = 0; r < 4; r++)
                accL[(cw * 16 + t * 4 + r) * 64 + lane] = acc[t][r];
        if (cw == 0 && lane < 16) lL[lane] = lsum;
    }
    __syncthreads();

    if (jh == 0) {
        const float rl = gamma[0] / (lsum + lL[n]);
#pragma unroll
        for (int t = 0; t < 4; t++) {
#pragma unroll
            for (int r = 0; r < 4; r++) {
                const int c = cb + t * 16 + q4 * 4 + r;
                const size_t idx = (size_t)(b * CH + c) * NN + i0 + n;
                const float a = acc[t][r] + accL[(cw * 16 + t * 4 + r) * 64 + lane];
                out[idx] = a * rl + x[idx];
            }
        }
    }
}

extern "C" void kernel_launch(void* const* d_in, const int* in_sizes, int n_in,
                              void* d_out, int out_size, void* d_ws, size_t ws_size,
                              hipStream_t stream) {
    (void)in_sizes; (void)n_in; (void)out_size; (void)ws_size;
    const float* x     = (const float*)d_in[0];
    const float* Wq    = (const float*)d_in[1];
    const float* bq    = (const float*)d_in[2];
    const float* Wk    = (const float*)d_in[3];
    const float* bk    = (const float*)d_in[4];
    const float* Wv    = (const float*)d_in[5];
    const float* bv    = (const float*)d_in[6];
    const float* Wr    = (const float*)d_in[7];
    // d_in[8] = br: j-constant logit shift -> softmax-invariant, dropped.
    const float* gamma = (const float*)d_in[9];
    float* out = (float*)d_out;
    unsigned short* ws = (unsigned short*)d_ws;

    wrepack_kernel<<<80, 256, 0, stream>>>(Wq, Wk, Wv, ws);
    proj_kernel<<<dim3(64, 8), 256, 0, stream>>>(x, bq, bk, bv, Wr, ws);
    attn_kernel<<<dim3(8, 128), 256, 0, stream>>>(x, gamma, ws, out);
}